// Round 6
// baseline (1172.552 us; speedup 1.0000x reference)
//
#include <hip/hip_runtime.h>
#include <cstdint>
#include <cstddef>

// =====================================================================
// Network_28862180229296: 3-layer heterogeneous message passing + pooling + MLP
//
// Transposed formulation: hs_j = sum_k (A_k x_i) @ W_k   (segment-sum is linear)
// FUSED: each block aggregates its 64-row tile for pair k directly into LDS
// (fp32), then does the 64x64 LDS x global-W GEMM, accumulating across pairs;
// epilogue applies residual (layer 2) + relu and stores bf16.
//
// R6 changes vs R5 (R5: 59% stall, serialized addr-load -> gather chains):
//  - gather loop software-pipelined: next quad's (col,val) prefetched before
//    current quad's gathers issue -> addresses always ready, gathers of
//    consecutive iterations overlap (critical path ~= gather latency only)
//  - k_pool2 + k_mlp fused into k_tail (one launch, pooled stays in LDS)
//  - everything else (bf16 activations, heavy-first order, W from L1) kept
// =====================================================================

namespace {

constexpr int NRr[5]  = {50000, 100000, 100000, 40000, 20000};
constexpr int PI[15]  = {0,1,2,3,4,0,0,0,0,1,1,1,2,2,3};
constexpr long long EOFF[15] = {0,400000,1200000,2000000,2320000,2480000,3280000,4080000,4400000,4560000,5360000,5680000,5840000,6160000,6320000};
constexpr int EK[15]  = {400000,800000,800000,320000,160000,800000,800000,320000,160000,800000,320000,160000,320000,160000,160000};
// row_ptr offsets per pair (N_j + 1 entries each)
constexpr int POFF[15] = {0,50001,150002,250003,290004,310005,410006,510007,550008,570009,670010,710011,730012,770013,790014};
constexpr int PTR_TOT  = 810015;
// xs row offsets per rank
constexpr int XOFF[5]  = {0,50000,150000,250000,290000};
constexpr int XROWS    = 310000;
// pairs targeting each rank j (K-chunks of the stacked GEMM)
constexpr int NPJ[5]    = {1,2,3,4,5};
constexpr int POJ[5][5] = {{0,0,0,0,0},{1,5,0,0,0},{2,6,9,0,0},{3,7,10,12,0},{4,8,11,13,14}};
// heavy-first block -> (rank, row-tile): order rank 4,3,2,1,0
constexpr int HJT_CUM[6] = {0,313,938,2501,4064,4846};
constexpr int HRANK[5]   = {4,3,2,1,0};
constexpr int FUSED_BLOCKS = 4846;

// ---- workspace layout (bytes) ----
constexpr size_t WS_B16IN = 0;                      // ushort[310000*64] = 39,680,000
constexpr size_t WS_B16X  = 39680000;               // ushort[310000*64]
constexpr size_t WS_B16Y  = 79360000;               // ushort[310000*64]
constexpr size_t WS_PTR   = 119040000;              // int[810015] = 3,240,060
constexpr size_t WS_PSUM  = 122280064;              // double[5*128*64] = 327,680
constexpr size_t WS_PSQ   = WS_PSUM + 327680;
constexpr size_t WS_PMAX  = WS_PSQ  + 327680;       // float[5*128*64] = 163,840
constexpr size_t WS_PMIN  = WS_PMAX + 163840;
constexpr size_t WS_NEEDED = WS_PMIN + 163840;      // 123,263,104

struct XP  { const float* p[5]; };
struct XPB { const unsigned short* p[5]; };

} // namespace

// ---------------------------------------------------------------------
// bf16 helpers (RNE)
// ---------------------------------------------------------------------
static __device__ __forceinline__ unsigned int rne_bf16(float x) {
    unsigned int b = __float_as_uint(x);
    return (b + 0x7fffu + ((b >> 16) & 1u)) >> 16;
}
static __device__ __forceinline__ float4 bf16x4_to_f4(uint2 u) {
    float4 f;
    f.x = __uint_as_float(u.x << 16);
    f.y = __uint_as_float(u.x & 0xffff0000u);
    f.z = __uint_as_float(u.y << 16);
    f.w = __uint_as_float(u.y & 0xffff0000u);
    return f;
}
static __device__ __forceinline__ uint2 f4_to_bf16x4(float4 v) {
    uint2 st;
    st.x = rne_bf16(v.x) | (rne_bf16(v.y) << 16);
    st.y = rne_bf16(v.z) | (rne_bf16(v.w) << 16);
    return st;
}

// ---------------------------------------------------------------------
// diagnostic fallback (never fault on small ws)
// ---------------------------------------------------------------------
__global__ void k_diag(float* __restrict__ out, float v) {
    out[0] = v;
    out[1] = 0.f;
}

// ---------------------------------------------------------------------
// 0) convert fp32 inputs -> bf16 activation buffer
// ---------------------------------------------------------------------
__global__ __launch_bounds__(256) void k_cvt(XP xin, unsigned short* __restrict__ b16) {
    int q = blockIdx.x * 256 + threadIdx.x;   // quad index (4 channels)
    if (q >= XROWS * 16) return;
    int row = q >> 4;
    int rank = 0;
#pragma unroll
    for (int t = 1; t < 5; ++t) if (row >= XOFF[t]) rank = t;
    const float* src = xin.p[rank] + (size_t)(row - XOFF[rank]) * 64 + (q & 15) * 4;
    float4 v = *(const float4*)src;
    ((uint2*)b16)[q] = f4_to_bf16x4(v);
}

// ---------------------------------------------------------------------
// 1) per-pair CSR row_ptr: rptr[POFF[k]+r] = lower_bound(rows_k, r)
// ---------------------------------------------------------------------
__global__ __launch_bounds__(256) void k_ptr(const int* __restrict__ rows,
                                             int* __restrict__ rptr) {
    int tid = blockIdx.x * 256 + threadIdx.x;
    if (tid >= PTR_TOT) return;
    int k = 0;
#pragma unroll
    for (int t = 1; t < 15; ++t) if (tid >= POFF[t]) k = t;
    int r = tid - POFF[k];
    const int* rb = rows + EOFF[k];
    int lo = 0, hi = EK[k];
    while (lo < hi) {
        int mid = (lo + hi) >> 1;
        if (rb[mid] < r) lo = mid + 1; else hi = mid;
    }
    rptr[tid] = lo;
}

// ---------------------------------------------------------------------
// 2) fused aggregate + stacked GEMM + residual + relu  (bf16 activations)
// ---------------------------------------------------------------------
static __device__ __forceinline__ void fma4(float4& a, float s, const float4& b) {
    a.x += s * b.x; a.y += s * b.y; a.z += s * b.z; a.w += s * b.w;
}

__global__ __launch_bounds__(256) void k_fused(XPB xp,
                                               const int* __restrict__ cols,
                                               const float* __restrict__ vals,
                                               const int* __restrict__ rptr,
                                               const float* __restrict__ Wh,
                                               unsigned short* __restrict__ xout,
                                               int layer) {
    __shared__ __align__(16) float As[64][68];   // [row][chan] fp32, +4 pad

    int b = blockIdx.x;
    int seg = 0;
#pragma unroll
    for (int t = 1; t < 5; ++t) if (b >= HJT_CUM[t]) seg = t;
    int j  = HRANK[seg];
    int rt = b - HJT_CUM[seg];
    int r0 = rt * 64;
    int Nj = NRr[j];

    int tid  = threadIdx.x;
    int wave = tid >> 6;
    int lane = tid & 63;
    int sub  = lane >> 4;          // 0..3: which row of the 4 concurrent rows
    int q16  = lane & 15;          // channel-quad index within row
    int cq4  = q16 * 4;            // channel base
    int tr   = tid >> 4;           // 0..15 (GEMM row group)
    int tc   = tid & 15;           // 0..15 (GEMM col group)
    int tr4  = tr * 4;

    float4 acc0 = make_float4(0.f,0.f,0.f,0.f);
    float4 acc1 = acc0, acc2 = acc0, acc3 = acc0;

    const float* Wl = Wh + (size_t)layer * 15 * 4096;
    int nk = NPJ[j];
    for (int kc = 0; kc < nk; ++kc) {
        int pk = POJ[j][kc];
        // --- aggregate 64 rows of pair pk into As (bf16 gather, fp32 acc) ---
        const unsigned short* __restrict__ xsrc = xp.p[PI[pk]];
        const int*   __restrict__ cb = cols + EOFF[pk];
        const float* __restrict__ vb = vals + EOFF[pk];
        const int*   __restrict__ rp = rptr + POFF[pk];
#pragma unroll
        for (int rg = 0; rg < 4; ++rg) {
            int rr = wave * 16 + rg * 4 + sub;
            int r  = r0 + rr;
            float4 a0 = make_float4(0.f,0.f,0.f,0.f);
            float4 a1 = a0;
            if (r < Nj) {
                int ps = rp[r];
                int pe = rp[r + 1];
                int e  = ps;
                if (e + 4 <= pe) {
                    // prefetch first quad of (col,val)
                    int   c0 = cb[e],     c1 = cb[e + 1], c2 = cb[e + 2], c3 = cb[e + 3];
                    float v0 = vb[e],     v1 = vb[e + 1], v2 = vb[e + 2], v3 = vb[e + 3];
                    while (e + 8 <= pe) {
                        // prefetch NEXT quad before issuing current gathers
                        int   n0 = cb[e + 4], n1 = cb[e + 5], n2 = cb[e + 6], n3 = cb[e + 7];
                        float w0 = vb[e + 4], w1 = vb[e + 5], w2 = vb[e + 6], w3 = vb[e + 7];
                        uint2 g0 = *((const uint2*)(xsrc + (size_t)c0 * 64) + q16);
                        uint2 g1 = *((const uint2*)(xsrc + (size_t)c1 * 64) + q16);
                        uint2 g2 = *((const uint2*)(xsrc + (size_t)c2 * 64) + q16);
                        uint2 g3 = *((const uint2*)(xsrc + (size_t)c3 * 64) + q16);
                        fma4(a0, v0, bf16x4_to_f4(g0));
                        fma4(a1, v1, bf16x4_to_f4(g1));
                        fma4(a0, v2, bf16x4_to_f4(g2));
                        fma4(a1, v3, bf16x4_to_f4(g3));
                        c0 = n0; c1 = n1; c2 = n2; c3 = n3;
                        v0 = w0; v1 = w1; v2 = w2; v3 = w3;
                        e += 4;
                    }
                    // drain the prefetched quad
                    {
                        uint2 g0 = *((const uint2*)(xsrc + (size_t)c0 * 64) + q16);
                        uint2 g1 = *((const uint2*)(xsrc + (size_t)c1 * 64) + q16);
                        uint2 g2 = *((const uint2*)(xsrc + (size_t)c2 * 64) + q16);
                        uint2 g3 = *((const uint2*)(xsrc + (size_t)c3 * 64) + q16);
                        fma4(a0, v0, bf16x4_to_f4(g0));
                        fma4(a1, v1, bf16x4_to_f4(g1));
                        fma4(a0, v2, bf16x4_to_f4(g2));
                        fma4(a1, v3, bf16x4_to_f4(g3));
                        e += 4;
                    }
                }
                for (; e < pe; ++e) {
                    int   c0 = cb[e];
                    float v0 = vb[e];
                    uint2 g0 = *((const uint2*)(xsrc + (size_t)c0 * 64) + q16);
                    fma4(a0, v0, bf16x4_to_f4(g0));
                }
                a0.x += a1.x; a0.y += a1.y; a0.z += a1.z; a0.w += a1.w;
            }
            *(float4*)&As[rr][cq4] = a0;
        }
        __syncthreads();
        // --- 64x64x64 GEMM: As (LDS) x W_k (global, L1-resident broadcast) ---
        const float* Wb = Wl + pk * 4096;
#pragma unroll
        for (int d = 0; d < 64; d += 4) {
            float4 b0 = *(const float4*)(Wb + (size_t)(d + 0) * 64 + tc * 4);
            float4 b1 = *(const float4*)(Wb + (size_t)(d + 1) * 64 + tc * 4);
            float4 b2 = *(const float4*)(Wb + (size_t)(d + 2) * 64 + tc * 4);
            float4 b3 = *(const float4*)(Wb + (size_t)(d + 3) * 64 + tc * 4);
            float4 a0 = *(const float4*)&As[tr4 + 0][d];
            float4 a1 = *(const float4*)&As[tr4 + 1][d];
            float4 a2 = *(const float4*)&As[tr4 + 2][d];
            float4 a3 = *(const float4*)&As[tr4 + 3][d];
            fma4(acc0, a0.x, b0); fma4(acc0, a0.y, b1); fma4(acc0, a0.z, b2); fma4(acc0, a0.w, b3);
            fma4(acc1, a1.x, b0); fma4(acc1, a1.y, b1); fma4(acc1, a1.z, b2); fma4(acc1, a1.w, b3);
            fma4(acc2, a2.x, b0); fma4(acc2, a2.y, b1); fma4(acc2, a2.z, b2); fma4(acc2, a2.w, b3);
            fma4(acc3, a3.x, b0); fma4(acc3, a3.y, b1); fma4(acc3, a3.z, b2); fma4(acc3, a3.w, b3);
        }
        __syncthreads();   // protect As rewrite next iteration
    }

    // epilogue: (+ residual at layer 2 from layer input), relu, store bf16
    float4 accs[4] = {acc0, acc1, acc2, acc3};
#pragma unroll
    for (int i = 0; i < 4; ++i) {
        int r = r0 + tr4 + i;
        if (r < Nj) {
            float4 h = accs[i];
            if (layer == 2) {
                uint2 gres = *((const uint2*)(xp.p[j] + (size_t)r * 64) + tc);
                float4 old = bf16x4_to_f4(gres);
                h.x += old.x; h.y += old.y; h.z += old.z; h.w += old.w;
            }
            h.x = fmaxf(h.x, 0.f); h.y = fmaxf(h.y, 0.f);
            h.z = fmaxf(h.z, 0.f); h.w = fmaxf(h.w, 0.f);
            *((uint2*)(xout + (size_t)(XOFF[j] + r) * 64) + tc) = f4_to_bf16x4(h);
        }
    }
}

// ---------------------------------------------------------------------
// 3) pooling stage 1: per-(rank, block) partial sum/sumsq(f64)/max/min
// ---------------------------------------------------------------------
__global__ __launch_bounds__(256) void k_pool1(const unsigned short* __restrict__ xs,
                                               double* __restrict__ psum,
                                               double* __restrict__ psq,
                                               float* __restrict__ pmax,
                                               float* __restrict__ pmin) {
    int rank = blockIdx.x >> 7;
    int blk  = blockIdx.x & 127;
    int c    = threadIdx.x & 63;
    int sub  = threadIdx.x >> 6;
    int N = NRr[rank];
    const unsigned short* xb = xs + (size_t)XOFF[rank] * 64;
    double s = 0.0, q = 0.0;
    float mx = -3.4e38f, mn = 3.4e38f;
    for (int r = blk * 4 + sub; r < N; r += 512) {
        float v = __uint_as_float(((unsigned int)xb[(size_t)r * 64 + c]) << 16);
        s += v; q += (double)v * (double)v;
        mx = fmaxf(mx, v); mn = fminf(mn, v);
    }
    __shared__ double ls[4][64], lq[4][64];
    __shared__ float lmx[4][64], lmn[4][64];
    ls[sub][c] = s; lq[sub][c] = q; lmx[sub][c] = mx; lmn[sub][c] = mn;
    __syncthreads();
    if (sub == 0) {
#pragma unroll
        for (int t = 1; t < 4; ++t) {
            s += ls[t][c]; q += lq[t][c];
            mx = fmaxf(mx, lmx[t][c]); mn = fminf(mn, lmn[t][c]);
        }
        int idx = (rank * 128 + blk) * 64 + c;
        psum[idx] = s; psq[idx] = q; pmax[idx] = mx; pmin[idx] = mn;
    }
}

// ---------------------------------------------------------------------
// 4) fused pooling stage 2 + MLP: 1284 -> 512 -> 128 -> 64 -> 2
// ---------------------------------------------------------------------
__global__ __launch_bounds__(512) void k_tail(const double* __restrict__ psum,
                                              const double* __restrict__ psq,
                                              const float* __restrict__ pmax,
                                              const float* __restrict__ pmin,
                                              const float* __restrict__ gf,
                                              const float* __restrict__ w1, const float* __restrict__ b1,
                                              const float* __restrict__ w2, const float* __restrict__ b2,
                                              const float* __restrict__ w3, const float* __restrict__ b3,
                                              const float* __restrict__ w4, const float* __restrict__ b4,
                                              float* __restrict__ out) {
    __shared__ float sp[1284];
    __shared__ float h1[512];
    __shared__ float h2[128];
    __shared__ float h3[64];
    int tid = threadIdx.x;
    // pool stage 2 -> sp (first 320 threads: rank = tid/64, channel = tid%64)
    if (tid < 320) {
        int rank = tid >> 6;
        int c    = tid & 63;
        double s = 0.0, q = 0.0;
        float mx = -3.4e38f, mn = 3.4e38f;
        for (int b = 0; b < 128; ++b) {
            int idx = (rank * 128 + b) * 64 + c;
            s += psum[idx]; q += psq[idx];
            mx = fmaxf(mx, pmax[idx]); mn = fminf(mn, pmin[idx]);
        }
        double N = (double)NRr[rank];
        double mean = s / N;
        double var  = q / N - mean * mean;
        if (var < 0.0) var = 0.0;
        double sd = sqrt(var == 0.0 ? 1e-6 : var);
        sp[rank * 256 + c]       = (float)mean;
        sp[rank * 256 + 64 + c]  = (float)sd;
        sp[rank * 256 + 128 + c] = mx;
        sp[rank * 256 + 192 + c] = mn;
        if (rank == 0 && c < 4) sp[1280 + c] = gf[c];
    }
    __syncthreads();
    {
        float a = 0.f;
        for (int k2 = 0; k2 < 1284; ++k2) a += sp[k2] * w1[k2 * 512 + tid];
        h1[tid] = fmaxf(a + b1[tid], 0.f);
    }
    __syncthreads();
    if (tid < 128) {
        float a = 0.f;
        for (int k2 = 0; k2 < 512; ++k2) a += h1[k2] * w2[k2 * 128 + tid];
        h2[tid] = fmaxf(a + b2[tid], 0.f);
    }
    __syncthreads();
    if (tid < 64) {
        float a = 0.f;
        for (int k2 = 0; k2 < 128; ++k2) a += h2[k2] * w3[k2 * 64 + tid];
        h3[tid] = fmaxf(a + b3[tid], 0.f);
    }
    __syncthreads();
    if (tid < 2) {
        float a = 0.f;
        for (int k2 = 0; k2 < 64; ++k2) a += h3[k2] * w4[k2 * 2 + tid];
        a += b4[tid];
        if (tid == 1) a = a * a;
        out[tid] = a;
    }
}

// ---------------------------------------------------------------------
extern "C" void kernel_launch(void* const* d_in, const int* in_sizes, int n_in,
                              void* d_out, int out_size, void* d_ws, size_t ws_size,
                              hipStream_t stream) {
    if (ws_size < WS_NEEDED) {
        hipLaunchKernelGGL(k_diag, dim3(1), dim3(1), 0, stream,
                           (float*)d_out, (float)(ws_size >> 20));
        return;
    }

    const float* x0   = (const float*)d_in[0];
    const float* x1   = (const float*)d_in[1];
    const float* x2   = (const float*)d_in[2];
    const float* x3   = (const float*)d_in[3];
    const float* x4   = (const float*)d_in[4];
    const int*   rows = (const int*)d_in[5];
    const int*   cols = (const int*)d_in[6];
    const float* vals = (const float*)d_in[7];
    const float* gf   = (const float*)d_in[8];
    const float* Wh   = (const float*)d_in[9];
    const float* w1   = (const float*)d_in[10];
    const float* b1   = (const float*)d_in[11];
    const float* w2   = (const float*)d_in[12];
    const float* b2   = (const float*)d_in[13];
    const float* w3   = (const float*)d_in[14];
    const float* b3   = (const float*)d_in[15];
    const float* w4   = (const float*)d_in[16];
    const float* b4   = (const float*)d_in[17];

    char* ws = (char*)d_ws;
    unsigned short* b16in = (unsigned short*)(ws + WS_B16IN);
    unsigned short* b16x  = (unsigned short*)(ws + WS_B16X);
    unsigned short* b16y  = (unsigned short*)(ws + WS_B16Y);
    int*    rptr   = (int*)(ws + WS_PTR);
    double* psum   = (double*)(ws + WS_PSUM);
    double* psq    = (double*)(ws + WS_PSQ);
    float*  pmax   = (float*)(ws + WS_PMAX);
    float*  pmin   = (float*)(ws + WS_PMIN);

    XP xp_in; xp_in.p[0] = x0; xp_in.p[1] = x1; xp_in.p[2] = x2; xp_in.p[3] = x3; xp_in.p[4] = x4;
    hipLaunchKernelGGL(k_cvt, dim3((XROWS * 16 + 255) / 256), dim3(256), 0, stream, xp_in, b16in);
    hipLaunchKernelGGL(k_ptr, dim3((PTR_TOT + 255) / 256), dim3(256), 0, stream, rows, rptr);

    XPB xb_in, xb_x, xb_y;
    for (int i = 0; i < 5; ++i) {
        xb_in.p[i] = b16in + (size_t)XOFF[i] * 64;
        xb_x.p[i]  = b16x  + (size_t)XOFF[i] * 64;
        xb_y.p[i]  = b16y  + (size_t)XOFF[i] * 64;
    }

    // layer 0: b16in -> b16x ; layer 1: b16x -> b16y ; layer 2: b16y -> b16x (+residual)
    hipLaunchKernelGGL(k_fused, dim3(FUSED_BLOCKS), dim3(256), 0, stream,
                       xb_in, cols, vals, rptr, Wh, b16x, 0);
    hipLaunchKernelGGL(k_fused, dim3(FUSED_BLOCKS), dim3(256), 0, stream,
                       xb_x, cols, vals, rptr, Wh, b16y, 1);
    hipLaunchKernelGGL(k_fused, dim3(FUSED_BLOCKS), dim3(256), 0, stream,
                       xb_y, cols, vals, rptr, Wh, b16x, 2);

    hipLaunchKernelGGL(k_pool1, dim3(5 * 128), dim3(256), 0, stream, b16x, psum, psq, pmax, pmin);
    hipLaunchKernelGGL(k_tail, dim3(1), dim3(512), 0, stream, psum, psq, pmax, pmin, gf,
                       w1, b1, w2, b2, w3, b3, w4, b4, (float*)d_out);
}

// Round 7
// 1150.952 us; speedup vs baseline: 1.0188x; 1.0188x over previous
//
#include <hip/hip_runtime.h>
#include <cstdint>
#include <cstddef>

// =====================================================================
// Network_28862180229296: 3-layer heterogeneous message passing + pooling + MLP
//
// Transposed formulation: hs_j = sum_k (A_k x_i) @ W_k   (segment-sum is linear)
//
// R7 structure: ONE WAVE per 16-row output tile, ZERO barriers.
//  - wave gathers all nk pairs for its 16 rows into private LDS (bf16,
//    K-stacked: As[16][64*nk]) -> long uninterrupted gather phase
//  - GEMM on MFMA (mfma_f32_16x16x32_bf16): A-frag = ds_read_b128 from own
//    LDS slice, B-frag = pre-transposed bf16 WT[n][k] from global (L1)
//  - epilogue: C via LDS (union; ordered by data dependency) -> coalesced
//    bf16 stores, +residual (layer 2) + relu
//  - all N_j divisible by 16 -> no row guards anywhere
// =====================================================================

namespace {

constexpr int NRr[5]  = {50000, 100000, 100000, 40000, 20000};
constexpr int PI[15]  = {0,1,2,3,4,0,0,0,0,1,1,1,2,2,3};
constexpr long long EOFF[15] = {0,400000,1200000,2000000,2320000,2480000,3280000,4080000,4400000,4560000,5360000,5680000,5840000,6160000,6320000};
constexpr int EK[15]  = {400000,800000,800000,320000,160000,800000,800000,320000,160000,800000,320000,160000,320000,160000,160000};
constexpr int POFF[15] = {0,50001,150002,250003,290004,310005,410006,510007,550008,570009,670010,710011,730012,770013,790014};
constexpr int PTR_TOT  = 810015;
constexpr int XOFF[5]  = {0,50000,150000,250000,290000};
constexpr int XROWS    = 310000;
constexpr int NPJ[5]    = {1,2,3,4,5};
constexpr int POJ[5][5] = {{0,0,0,0,0},{1,5,0,0,0},{2,6,9,0,0},{3,7,10,12,0},{4,8,11,13,14}};
// 16-row tiles, heavy-first (rank 4: 40 e/row ... rank 0: 8 e/row)
// tiles/rank: r0=3125 r1=6250 r2=6250 r3=2500 r4=1250
constexpr int TCUM[6]  = {0,1250,3750,10000,16250,19375};
constexpr int TRANK[5] = {4,3,2,1,0};
constexpr int FUSED_BLOCKS = 19375;
constexpr int AS_STRIDE = 336;   // shorts per LDS row (320 + 16 pad)

// ---- workspace layout (bytes) ----
constexpr size_t WS_B16IN = 0;                      // ushort[310000*64] = 39,680,000
constexpr size_t WS_B16X  = 39680000;
constexpr size_t WS_B16Y  = 79360000;
constexpr size_t WS_PTR   = 119040000;              // int[810015] = 3,240,060
constexpr size_t WS_WT    = 122280064;              // ushort[3*15*4096] = 368,640
constexpr size_t WS_PSUM  = 122648704;              // double[5*128*64] = 327,680
constexpr size_t WS_PSQ   = WS_PSUM + 327680;
constexpr size_t WS_PMAX  = WS_PSQ  + 327680;       // float[5*128*64] = 163,840
constexpr size_t WS_PMIN  = WS_PMAX + 163840;
constexpr size_t WS_NEEDED = WS_PMIN + 163840;      // 123,631,744

struct XP  { const float* p[5]; };
struct XPB { const unsigned short* p[5]; };

} // namespace

typedef __attribute__((ext_vector_type(8))) short short8;
typedef __attribute__((ext_vector_type(4))) float f32x4;

// ---------------------------------------------------------------------
// bf16 helpers (RNE)
// ---------------------------------------------------------------------
static __device__ __forceinline__ unsigned int rne_bf16(float x) {
    unsigned int b = __float_as_uint(x);
    return (b + 0x7fffu + ((b >> 16) & 1u)) >> 16;
}
static __device__ __forceinline__ float4 bf16x4_to_f4(uint2 u) {
    float4 f;
    f.x = __uint_as_float(u.x << 16);
    f.y = __uint_as_float(u.x & 0xffff0000u);
    f.z = __uint_as_float(u.y << 16);
    f.w = __uint_as_float(u.y & 0xffff0000u);
    return f;
}
static __device__ __forceinline__ uint2 f4_to_bf16x4(float4 v) {
    uint2 st;
    st.x = rne_bf16(v.x) | (rne_bf16(v.y) << 16);
    st.y = rne_bf16(v.z) | (rne_bf16(v.w) << 16);
    return st;
}

// ---------------------------------------------------------------------
__global__ void k_diag(float* __restrict__ out, float v) {
    out[0] = v;
    out[1] = 0.f;
}

// ---------------------------------------------------------------------
// 0a) convert fp32 inputs -> unified bf16 activation buffer
// ---------------------------------------------------------------------
__global__ __launch_bounds__(256) void k_cvt(XP xin, unsigned short* __restrict__ b16) {
    int q = blockIdx.x * 256 + threadIdx.x;   // quad index (4 channels)
    if (q >= XROWS * 16) return;
    int row = q >> 4;
    int rank = 0;
#pragma unroll
    for (int t = 1; t < 5; ++t) if (row >= XOFF[t]) rank = t;
    const float* src = xin.p[rank] + (size_t)(row - XOFF[rank]) * 64 + (q & 15) * 4;
    float4 v = *(const float4*)src;
    ((uint2*)b16)[q] = f4_to_bf16x4(v);
}

// ---------------------------------------------------------------------
// 0b) transpose+convert W: WT[l][p][n][k] (bf16) from Wh[l][p][k][n] (fp32)
// ---------------------------------------------------------------------
__global__ __launch_bounds__(256) void k_cvtw(const float* __restrict__ Wh,
                                              unsigned short* __restrict__ WT) {
    int tid = blockIdx.x * 256 + threadIdx.x;
    if (tid >= 3 * 15 * 4096) return;
    int lp = tid >> 12;
    int nk_ = tid & 4095;
    int n = nk_ >> 6;
    int k = nk_ & 63;
    float w = Wh[(size_t)lp * 4096 + k * 64 + n];
    WT[tid] = (unsigned short)rne_bf16(w);
}

// ---------------------------------------------------------------------
// 1) per-pair CSR row_ptr: rptr[POFF[k]+r] = lower_bound(rows_k, r)
// ---------------------------------------------------------------------
__global__ __launch_bounds__(256) void k_ptr(const int* __restrict__ rows,
                                             int* __restrict__ rptr) {
    int tid = blockIdx.x * 256 + threadIdx.x;
    if (tid >= PTR_TOT) return;
    int k = 0;
#pragma unroll
    for (int t = 1; t < 15; ++t) if (tid >= POFF[t]) k = t;
    int r = tid - POFF[k];
    const int* rb = rows + EOFF[k];
    int lo = 0, hi = EK[k];
    while (lo < hi) {
        int mid = (lo + hi) >> 1;
        if (rb[mid] < r) lo = mid + 1; else hi = mid;
    }
    rptr[tid] = lo;
}

// ---------------------------------------------------------------------
// 2) fused aggregate (bf16 gather) + MFMA GEMM + residual + relu
//    one wave per 16-row tile; no barriers
// ---------------------------------------------------------------------
static __device__ __forceinline__ void fma4(float4& a, float s, const float4& b) {
    a.x += s * b.x; a.y += s * b.y; a.z += s * b.z; a.w += s * b.w;
}

__global__ __launch_bounds__(64) void k_fused(XPB xp,
                                              const int* __restrict__ cols,
                                              const float* __restrict__ vals,
                                              const int* __restrict__ rptr,
                                              const unsigned short* __restrict__ WT,
                                              unsigned short* __restrict__ xout,
                                              int layer) {
    // 10,752 B: As[16][336] bf16 for MFMA A; reused as C[16][65] fp32 in epilogue
    __shared__ union {
        short a[16 * AS_STRIDE];
        float c[16 * 65];
    } S;

    int b = blockIdx.x;
    int seg = 0;
#pragma unroll
    for (int t = 1; t < 5; ++t) if (b >= TCUM[t]) seg = t;
    int j  = TRANK[seg];
    int r0 = (b - TCUM[seg]) * 16;

    int lane = threadIdx.x;
    int sub  = lane >> 4;          // 0..3
    int q16  = lane & 15;          // 0..15
    int nk = NPJ[j];

    // ---- gather phase: all pairs, 16 rows, 4 rows concurrently ----
    for (int kc = 0; kc < nk; ++kc) {
        int pk = POJ[j][kc];
        const unsigned short* __restrict__ xsrc = xp.p[PI[pk]];
        const int*   __restrict__ cb = cols + EOFF[pk];
        const float* __restrict__ vb = vals + EOFF[pk];
        const int*   __restrict__ rp = rptr + POFF[pk];
#pragma unroll
        for (int rg = 0; rg < 4; ++rg) {
            int rr = rg * 4 + sub;
            int r  = r0 + rr;
            int ps = rp[r];
            int pe = rp[r + 1];
            float4 a0 = make_float4(0.f,0.f,0.f,0.f);
            float4 a1 = a0;
            int e = ps;
            for (; e + 3 < pe; e += 4) {
                int   c0 = cb[e],     c1 = cb[e + 1], c2 = cb[e + 2], c3 = cb[e + 3];
                float v0 = vb[e],     v1 = vb[e + 1], v2 = vb[e + 2], v3 = vb[e + 3];
                uint2 g0 = *((const uint2*)(xsrc + (size_t)c0 * 64) + q16);
                uint2 g1 = *((const uint2*)(xsrc + (size_t)c1 * 64) + q16);
                uint2 g2 = *((const uint2*)(xsrc + (size_t)c2 * 64) + q16);
                uint2 g3 = *((const uint2*)(xsrc + (size_t)c3 * 64) + q16);
                fma4(a0, v0, bf16x4_to_f4(g0));
                fma4(a1, v1, bf16x4_to_f4(g1));
                fma4(a0, v2, bf16x4_to_f4(g2));
                fma4(a1, v3, bf16x4_to_f4(g3));
            }
            for (; e < pe; ++e) {
                int   c0 = cb[e];
                float v0 = vb[e];
                uint2 g0 = *((const uint2*)(xsrc + (size_t)c0 * 64) + q16);
                fma4(a0, v0, bf16x4_to_f4(g0));
            }
            a0.x += a1.x; a0.y += a1.y; a0.z += a1.z; a0.w += a1.w;
            *(uint2*)&S.a[rr * AS_STRIDE + kc * 64 + q16 * 4] = f4_to_bf16x4(a0);
        }
    }

    // ---- MFMA phase: D[16x64] += As[16xK] x W[Kx64], K = 64*nk ----
    // A-frag: A[m=q16][k = quad*8 + j]; B-frag: B[k = quad*8 + j][n=q16]
    f32x4 d0 = {0.f,0.f,0.f,0.f};
    f32x4 d1 = d0, d2 = d0, d3 = d0;
    const unsigned short* WTl = WT + (size_t)layer * 15 * 4096;
    for (int kc = 0; kc < nk; ++kc) {
        const unsigned short* Wp = WTl + POJ[j][kc] * 4096;
#pragma unroll
        for (int h = 0; h < 2; ++h) {
            short8 af = *(const short8*)&S.a[q16 * AS_STRIDE + kc * 64 + h * 32 + sub * 8];
            short8 b0 = *(const short8*)(Wp + ( 0 + q16) * 64 + h * 32 + sub * 8);
            short8 b1 = *(const short8*)(Wp + (16 + q16) * 64 + h * 32 + sub * 8);
            short8 b2 = *(const short8*)(Wp + (32 + q16) * 64 + h * 32 + sub * 8);
            short8 b3 = *(const short8*)(Wp + (48 + q16) * 64 + h * 32 + sub * 8);
            d0 = __builtin_amdgcn_mfma_f32_16x16x32_bf16(af, b0, d0, 0, 0, 0);
            d1 = __builtin_amdgcn_mfma_f32_16x16x32_bf16(af, b1, d1, 0, 0, 0);
            d2 = __builtin_amdgcn_mfma_f32_16x16x32_bf16(af, b2, d2, 0, 0, 0);
            d3 = __builtin_amdgcn_mfma_f32_16x16x32_bf16(af, b3, d3, 0, 0, 0);
        }
    }

    // ---- epilogue: C layout col=lane&15, row=quad*4+reg -> LDS -> coalesced ----
    // (every d depends on every A-frag read, so LDS reuse is dependency-ordered)
#pragma unroll
    for (int g = 0; g < 4; ++g) {
        S.c[(sub * 4 + g) * 65 +  0 + q16] = d0[g];
        S.c[(sub * 4 + g) * 65 + 16 + q16] = d1[g];
        S.c[(sub * 4 + g) * 65 + 32 + q16] = d2[g];
        S.c[(sub * 4 + g) * 65 + 48 + q16] = d3[g];
    }
    __builtin_amdgcn_s_waitcnt(0);   // drain lgkm before cross-lane LDS read (same wave)

    int row = lane >> 2;             // 0..15
    int qs  = lane & 3;              // 0..3 (16-channel segment)
    const float* Cr = S.c + row * 65 + qs * 16;
    float4 v0 = *(const float4*)(Cr + 0);
    float4 v1 = *(const float4*)(Cr + 4);
    float4 v2 = *(const float4*)(Cr + 8);
    float4 v3 = *(const float4*)(Cr + 12);
    if (layer == 2) {
        const uint4* res = (const uint4*)(xp.p[j] + (size_t)(r0 + row) * 64 + qs * 16);
        uint4 ra = res[0];
        uint4 rb = res[1];
        float4 o0 = bf16x4_to_f4(make_uint2(ra.x, ra.y));
        float4 o1 = bf16x4_to_f4(make_uint2(ra.z, ra.w));
        float4 o2 = bf16x4_to_f4(make_uint2(rb.x, rb.y));
        float4 o3 = bf16x4_to_f4(make_uint2(rb.z, rb.w));
        v0.x += o0.x; v0.y += o0.y; v0.z += o0.z; v0.w += o0.w;
        v1.x += o1.x; v1.y += o1.y; v1.z += o1.z; v1.w += o1.w;
        v2.x += o2.x; v2.y += o2.y; v2.z += o2.z; v2.w += o2.w;
        v3.x += o3.x; v3.y += o3.y; v3.z += o3.z; v3.w += o3.w;
    }
    v0.x = fmaxf(v0.x, 0.f); v0.y = fmaxf(v0.y, 0.f); v0.z = fmaxf(v0.z, 0.f); v0.w = fmaxf(v0.w, 0.f);
    v1.x = fmaxf(v1.x, 0.f); v1.y = fmaxf(v1.y, 0.f); v1.z = fmaxf(v1.z, 0.f); v1.w = fmaxf(v1.w, 0.f);
    v2.x = fmaxf(v2.x, 0.f); v2.y = fmaxf(v2.y, 0.f); v2.z = fmaxf(v2.z, 0.f); v2.w = fmaxf(v2.w, 0.f);
    v3.x = fmaxf(v3.x, 0.f); v3.y = fmaxf(v3.y, 0.f); v3.z = fmaxf(v3.z, 0.f); v3.w = fmaxf(v3.w, 0.f);
    uint2 s0 = f4_to_bf16x4(v0);
    uint2 s1 = f4_to_bf16x4(v1);
    uint2 s2 = f4_to_bf16x4(v2);
    uint2 s3 = f4_to_bf16x4(v3);
    uint4* dst = (uint4*)(xout + (size_t)(XOFF[j] + r0 + row) * 64 + qs * 16);
    dst[0] = make_uint4(s0.x, s0.y, s1.x, s1.y);
    dst[1] = make_uint4(s2.x, s2.y, s3.x, s3.y);
}

// ---------------------------------------------------------------------
// 3) pooling stage 1: per-(rank, block) partial sum/sumsq(f64)/max/min
// ---------------------------------------------------------------------
__global__ __launch_bounds__(256) void k_pool1(const unsigned short* __restrict__ xs,
                                               double* __restrict__ psum,
                                               double* __restrict__ psq,
                                               float* __restrict__ pmax,
                                               float* __restrict__ pmin) {
    int rank = blockIdx.x >> 7;
    int blk  = blockIdx.x & 127;
    int c    = threadIdx.x & 63;
    int sub  = threadIdx.x >> 6;
    int N = NRr[rank];
    const unsigned short* xb = xs + (size_t)XOFF[rank] * 64;
    double s = 0.0, q = 0.0;
    float mx = -3.4e38f, mn = 3.4e38f;
    for (int r = blk * 4 + sub; r < N; r += 512) {
        float v = __uint_as_float(((unsigned int)xb[(size_t)r * 64 + c]) << 16);
        s += v; q += (double)v * (double)v;
        mx = fmaxf(mx, v); mn = fminf(mn, v);
    }
    __shared__ double ls[4][64], lq[4][64];
    __shared__ float lmx[4][64], lmn[4][64];
    ls[sub][c] = s; lq[sub][c] = q; lmx[sub][c] = mx; lmn[sub][c] = mn;
    __syncthreads();
    if (sub == 0) {
#pragma unroll
        for (int t = 1; t < 4; ++t) {
            s += ls[t][c]; q += lq[t][c];
            mx = fmaxf(mx, lmx[t][c]); mn = fminf(mn, lmn[t][c]);
        }
        int idx = (rank * 128 + blk) * 64 + c;
        psum[idx] = s; psq[idx] = q; pmax[idx] = mx; pmin[idx] = mn;
    }
}

// ---------------------------------------------------------------------
// 4) fused pooling stage 2 + MLP: 1284 -> 512 -> 128 -> 64 -> 2
// ---------------------------------------------------------------------
__global__ __launch_bounds__(512) void k_tail(const double* __restrict__ psum,
                                              const double* __restrict__ psq,
                                              const float* __restrict__ pmax,
                                              const float* __restrict__ pmin,
                                              const float* __restrict__ gf,
                                              const float* __restrict__ w1, const float* __restrict__ b1,
                                              const float* __restrict__ w2, const float* __restrict__ b2,
                                              const float* __restrict__ w3, const float* __restrict__ b3,
                                              const float* __restrict__ w4, const float* __restrict__ b4,
                                              float* __restrict__ out) {
    __shared__ float sp[1284];
    __shared__ float h1[512];
    __shared__ float h2[128];
    __shared__ float h3[64];
    int tid = threadIdx.x;
    if (tid < 320) {
        int rank = tid >> 6;
        int c    = tid & 63;
        double s = 0.0, q = 0.0;
        float mx = -3.4e38f, mn = 3.4e38f;
        for (int b = 0; b < 128; ++b) {
            int idx = (rank * 128 + b) * 64 + c;
            s += psum[idx]; q += psq[idx];
            mx = fmaxf(mx, pmax[idx]); mn = fminf(mn, pmin[idx]);
        }
        double N = (double)NRr[rank];
        double mean = s / N;
        double var  = q / N - mean * mean;
        if (var < 0.0) var = 0.0;
        double sd = sqrt(var == 0.0 ? 1e-6 : var);
        sp[rank * 256 + c]       = (float)mean;
        sp[rank * 256 + 64 + c]  = (float)sd;
        sp[rank * 256 + 128 + c] = mx;
        sp[rank * 256 + 192 + c] = mn;
        if (rank == 0 && c < 4) sp[1280 + c] = gf[c];
    }
    __syncthreads();
    {
        float a = 0.f;
        for (int k2 = 0; k2 < 1284; ++k2) a += sp[k2] * w1[k2 * 512 + tid];
        h1[tid] = fmaxf(a + b1[tid], 0.f);
    }
    __syncthreads();
    if (tid < 128) {
        float a = 0.f;
        for (int k2 = 0; k2 < 512; ++k2) a += h1[k2] * w2[k2 * 128 + tid];
        h2[tid] = fmaxf(a + b2[tid], 0.f);
    }
    __syncthreads();
    if (tid < 64) {
        float a = 0.f;
        for (int k2 = 0; k2 < 128; ++k2) a += h2[k2] * w3[k2 * 64 + tid];
        h3[tid] = fmaxf(a + b3[tid], 0.f);
    }
    __syncthreads();
    if (tid < 2) {
        float a = 0.f;
        for (int k2 = 0; k2 < 64; ++k2) a += h3[k2] * w4[k2 * 2 + tid];
        a += b4[tid];
        if (tid == 1) a = a * a;
        out[tid] = a;
    }
}

// ---------------------------------------------------------------------
extern "C" void kernel_launch(void* const* d_in, const int* in_sizes, int n_in,
                              void* d_out, int out_size, void* d_ws, size_t ws_size,
                              hipStream_t stream) {
    if (ws_size < WS_NEEDED) {
        hipLaunchKernelGGL(k_diag, dim3(1), dim3(1), 0, stream,
                           (float*)d_out, (float)(ws_size >> 20));
        return;
    }

    const float* x0   = (const float*)d_in[0];
    const float* x1   = (const float*)d_in[1];
    const float* x2   = (const float*)d_in[2];
    const float* x3   = (const float*)d_in[3];
    const float* x4   = (const float*)d_in[4];
    const int*   rows = (const int*)d_in[5];
    const int*   cols = (const int*)d_in[6];
    const float* vals = (const float*)d_in[7];
    const float* gf   = (const float*)d_in[8];
    const float* Wh   = (const float*)d_in[9];
    const float* w1   = (const float*)d_in[10];
    const float* b1   = (const float*)d_in[11];
    const float* w2   = (const float*)d_in[12];
    const float* b2   = (const float*)d_in[13];
    const float* w3   = (const float*)d_in[14];
    const float* b3   = (const float*)d_in[15];
    const float* w4   = (const float*)d_in[16];
    const float* b4   = (const float*)d_in[17];

    char* ws = (char*)d_ws;
    unsigned short* b16in = (unsigned short*)(ws + WS_B16IN);
    unsigned short* b16x  = (unsigned short*)(ws + WS_B16X);
    unsigned short* b16y  = (unsigned short*)(ws + WS_B16Y);
    int*    rptr   = (int*)(ws + WS_PTR);
    unsigned short* WT = (unsigned short*)(ws + WS_WT);
    double* psum   = (double*)(ws + WS_PSUM);
    double* psq    = (double*)(ws + WS_PSQ);
    float*  pmax   = (float*)(ws + WS_PMAX);
    float*  pmin   = (float*)(ws + WS_PMIN);

    XP xp_in; xp_in.p[0] = x0; xp_in.p[1] = x1; xp_in.p[2] = x2; xp_in.p[3] = x3; xp_in.p[4] = x4;
    hipLaunchKernelGGL(k_cvt, dim3((XROWS * 16 + 255) / 256), dim3(256), 0, stream, xp_in, b16in);
    hipLaunchKernelGGL(k_cvtw, dim3((3 * 15 * 4096 + 255) / 256), dim3(256), 0, stream, Wh, WT);
    hipLaunchKernelGGL(k_ptr, dim3((PTR_TOT + 255) / 256), dim3(256), 0, stream, rows, rptr);

    XPB xb_in, xb_x, xb_y;
    for (int i = 0; i < 5; ++i) {
        xb_in.p[i] = b16in + (size_t)XOFF[i] * 64;
        xb_x.p[i]  = b16x  + (size_t)XOFF[i] * 64;
        xb_y.p[i]  = b16y  + (size_t)XOFF[i] * 64;
    }

    // layer 0: b16in -> b16x ; layer 1: b16x -> b16y ; layer 2: b16y -> b16x (+residual)
    hipLaunchKernelGGL(k_fused, dim3(FUSED_BLOCKS), dim3(64), 0, stream,
                       xb_in, cols, vals, rptr, WT, b16x, 0);
    hipLaunchKernelGGL(k_fused, dim3(FUSED_BLOCKS), dim3(64), 0, stream,
                       xb_x, cols, vals, rptr, WT, b16y, 1);
    hipLaunchKernelGGL(k_fused, dim3(FUSED_BLOCKS), dim3(64), 0, stream,
                       xb_y, cols, vals, rptr, WT, b16x, 2);

    hipLaunchKernelGGL(k_pool1, dim3(5 * 128), dim3(256), 0, stream, b16x, psum, psq, pmax, pmin);
    hipLaunchKernelGGL(k_tail, dim3(1), dim3(512), 0, stream, psum, psq, pmax, pmin, gf,
                       w1, b1, w2, b2, w3, b3, w4, b4, (float*)d_out);
}

// Round 8
// 926.817 us; speedup vs baseline: 1.2651x; 1.2418x over previous
//
#include <hip/hip_runtime.h>
#include <cstdint>
#include <cstddef>

// =====================================================================
// Network_28862180229296: 3-layer heterogeneous message passing + pooling + MLP
//
// Transposed formulation: hs_j = sum_k (A_k x_i) @ W_k   (segment-sum is linear)
//
// R8 structure: one wave per 16-row tile, no barriers, NO LDS A-staging.
//  - gather lane-mapping == MFMA A-frag layout: lane owns row m=lane&15,
//    channel slice (lane>>4)*8 (+0/+32 for the two K-halves of 16x16x32).
//    Each edge: 2 x uint4 bf16 loads, fp32 accum in regs, in-register cvt
//    to short8 A-frag. 16 rows gathered concurrently, unroll x2.
//  - B-frag from pre-transposed bf16 WT[n][k] (global, L1 broadcast)
//  - LDS only for the C epilogue transpose (16x65 fp32 = 4.2 KB) ->
//    occupancy VGPR-bound (~24-32 waves/CU), was LDS-bound at 14
// =====================================================================

namespace {

constexpr int NRr[5]  = {50000, 100000, 100000, 40000, 20000};
constexpr int PI[15]  = {0,1,2,3,4,0,0,0,0,1,1,1,2,2,3};
constexpr long long EOFF[15] = {0,400000,1200000,2000000,2320000,2480000,3280000,4080000,4400000,4560000,5360000,5680000,5840000,6160000,6320000};
constexpr int EK[15]  = {400000,800000,800000,320000,160000,800000,800000,320000,160000,800000,320000,160000,320000,160000,160000};
constexpr int POFF[15] = {0,50001,150002,250003,290004,310005,410006,510007,550008,570009,670010,710011,730012,770013,790014};
constexpr int PTR_TOT  = 810015;
constexpr int XOFF[5]  = {0,50000,150000,250000,290000};
constexpr int XROWS    = 310000;
constexpr int NPJ[5]    = {1,2,3,4,5};
constexpr int POJ[5][5] = {{0,0,0,0,0},{1,5,0,0,0},{2,6,9,0,0},{3,7,10,12,0},{4,8,11,13,14}};
// 16-row tiles, heavy-first (rank 4: 40 e/row ... rank 0: 8 e/row)
constexpr int TCUM[6]  = {0,1250,3750,10000,16250,19375};
constexpr int TRANK[5] = {4,3,2,1,0};
constexpr int FUSED_BLOCKS = 19375;

// ---- workspace layout (bytes) ----
constexpr size_t WS_B16IN = 0;                      // ushort[310000*64] = 39,680,000
constexpr size_t WS_B16X  = 39680000;
constexpr size_t WS_B16Y  = 79360000;
constexpr size_t WS_PTR   = 119040000;              // int[810015] = 3,240,060
constexpr size_t WS_WT    = 122280064;              // ushort[3*15*4096] = 368,640
constexpr size_t WS_PSUM  = 122648704;              // double[5*128*64] = 327,680
constexpr size_t WS_PSQ   = WS_PSUM + 327680;
constexpr size_t WS_PMAX  = WS_PSQ  + 327680;       // float[5*128*64] = 163,840
constexpr size_t WS_PMIN  = WS_PMAX + 163840;
constexpr size_t WS_NEEDED = WS_PMIN + 163840;      // 123,631,744

struct XP  { const float* p[5]; };
struct XPB { const unsigned short* p[5]; };

} // namespace

typedef __attribute__((ext_vector_type(8))) short short8;
typedef __attribute__((ext_vector_type(4))) float f32x4;

// ---------------------------------------------------------------------
// bf16 helpers (RNE)
// ---------------------------------------------------------------------
static __device__ __forceinline__ unsigned int rne_bf16(float x) {
    unsigned int b = __float_as_uint(x);
    return (b + 0x7fffu + ((b >> 16) & 1u)) >> 16;
}
static __device__ __forceinline__ float4 bf16x4_to_f4(uint2 u) {
    float4 f;
    f.x = __uint_as_float(u.x << 16);
    f.y = __uint_as_float(u.x & 0xffff0000u);
    f.z = __uint_as_float(u.y << 16);
    f.w = __uint_as_float(u.y & 0xffff0000u);
    return f;
}
static __device__ __forceinline__ uint2 f4_to_bf16x4(float4 v) {
    uint2 st;
    st.x = rne_bf16(v.x) | (rne_bf16(v.y) << 16);
    st.y = rne_bf16(v.z) | (rne_bf16(v.w) << 16);
    return st;
}
static __device__ __forceinline__ void fma4(float4& a, float s, const float4& b) {
    a.x += s * b.x; a.y += s * b.y; a.z += s * b.z; a.w += s * b.w;
}
// fma a 16B bf16x8 gather into two float4 accumulators
static __device__ __forceinline__ void fma8(float4& alo, float4& ahi, float s, uint4 g) {
    fma4(alo, s, bf16x4_to_f4(make_uint2(g.x, g.y)));
    fma4(ahi, s, bf16x4_to_f4(make_uint2(g.z, g.w)));
}
static __device__ __forceinline__ short8 pack_af(float4 lo, float4 hi) {
    uint2 pa = f4_to_bf16x4(lo);
    uint2 pb = f4_to_bf16x4(hi);
    short8 af;
    ((unsigned int*)&af)[0] = pa.x;
    ((unsigned int*)&af)[1] = pa.y;
    ((unsigned int*)&af)[2] = pb.x;
    ((unsigned int*)&af)[3] = pb.y;
    return af;
}

// ---------------------------------------------------------------------
__global__ void k_diag(float* __restrict__ out, float v) {
    out[0] = v;
    out[1] = 0.f;
}

// ---------------------------------------------------------------------
// 0a) convert fp32 inputs -> unified bf16 activation buffer
// ---------------------------------------------------------------------
__global__ __launch_bounds__(256) void k_cvt(XP xin, unsigned short* __restrict__ b16) {
    int q = blockIdx.x * 256 + threadIdx.x;   // quad index (4 channels)
    if (q >= XROWS * 16) return;
    int row = q >> 4;
    int rank = 0;
#pragma unroll
    for (int t = 1; t < 5; ++t) if (row >= XOFF[t]) rank = t;
    const float* src = xin.p[rank] + (size_t)(row - XOFF[rank]) * 64 + (q & 15) * 4;
    float4 v = *(const float4*)src;
    ((uint2*)b16)[q] = f4_to_bf16x4(v);
}

// ---------------------------------------------------------------------
// 0b) transpose+convert W: WT[l][p][n][k] (bf16) from Wh[l][p][k][n] (fp32)
// ---------------------------------------------------------------------
__global__ __launch_bounds__(256) void k_cvtw(const float* __restrict__ Wh,
                                              unsigned short* __restrict__ WT) {
    int tid = blockIdx.x * 256 + threadIdx.x;
    if (tid >= 3 * 15 * 4096) return;
    int lp = tid >> 12;
    int nk_ = tid & 4095;
    int n = nk_ >> 6;
    int k = nk_ & 63;
    float w = Wh[(size_t)lp * 4096 + k * 64 + n];
    WT[tid] = (unsigned short)rne_bf16(w);
}

// ---------------------------------------------------------------------
// 1) per-pair CSR row_ptr: rptr[POFF[k]+r] = lower_bound(rows_k, r)
// ---------------------------------------------------------------------
__global__ __launch_bounds__(256) void k_ptr(const int* __restrict__ rows,
                                             int* __restrict__ rptr) {
    int tid = blockIdx.x * 256 + threadIdx.x;
    if (tid >= PTR_TOT) return;
    int k = 0;
#pragma unroll
    for (int t = 1; t < 15; ++t) if (tid >= POFF[t]) k = t;
    int r = tid - POFF[k];
    const int* rb = rows + EOFF[k];
    int lo = 0, hi = EK[k];
    while (lo < hi) {
        int mid = (lo + hi) >> 1;
        if (rb[mid] < r) lo = mid + 1; else hi = mid;
    }
    rptr[tid] = lo;
}

// ---------------------------------------------------------------------
// 2) fused aggregate (reg-direct bf16 gather) + MFMA GEMM + residual + relu
//    one wave per 16-row tile; no barriers; LDS only for C epilogue
// ---------------------------------------------------------------------
__global__ __launch_bounds__(64, 6) void k_fused(XPB xp,
                                                 const int* __restrict__ cols,
                                                 const float* __restrict__ vals,
                                                 const int* __restrict__ rptr,
                                                 const unsigned short* __restrict__ WT,
                                                 unsigned short* __restrict__ xout,
                                                 int layer) {
    __shared__ float C[16 * 65];   // 4160 B, C-epilogue transpose only

    int b = blockIdx.x;
    int seg = 0;
#pragma unroll
    for (int t = 1; t < 5; ++t) if (b >= TCUM[t]) seg = t;
    int j  = TRANK[seg];
    int r0 = (b - TCUM[seg]) * 16;

    int lane = threadIdx.x;
    int m    = lane & 15;          // owned output row (A-frag m index / B-frag n index)
    int quad = lane >> 4;          // 0..3
    int s8   = quad * 8;           // channel-slice base (shorts) within a K-half

    f32x4 d0 = {0.f,0.f,0.f,0.f};
    f32x4 d1 = d0, d2 = d0, d3 = d0;

    const unsigned short* WTl = WT + (size_t)layer * 15 * 4096;
    int nk = NPJ[j];
    for (int kc = 0; kc < nk; ++kc) {
        int pk = POJ[j][kc];
        const unsigned short* __restrict__ xsrc = xp.p[PI[pk]];
        const int*   __restrict__ cb = cols + EOFF[pk];
        const float* __restrict__ vb = vals + EOFF[pk];
        const int*   __restrict__ rp = rptr + POFF[pk];

        // ---- gather this pair: 16 rows concurrently, edge-serial per row ----
        int ps = rp[r0 + m];
        int pe = rp[r0 + m + 1];
        float4 a0lo = make_float4(0.f,0.f,0.f,0.f), a0hi = a0lo;  // K-half 0
        float4 a1lo = a0lo, a1hi = a0lo;                          // K-half 1
        int e = ps;
        for (; e + 1 < pe; e += 2) {
            int   c0 = cb[e];
            int   c1 = cb[e + 1];
            float v0 = vb[e];
            float v1 = vb[e + 1];
            const unsigned short* r0p = xsrc + (size_t)c0 * 64;
            const unsigned short* r1p = xsrc + (size_t)c1 * 64;
            uint4 g00 = *(const uint4*)(r0p + s8);
            uint4 g01 = *(const uint4*)(r0p + 32 + s8);
            uint4 g10 = *(const uint4*)(r1p + s8);
            uint4 g11 = *(const uint4*)(r1p + 32 + s8);
            fma8(a0lo, a0hi, v0, g00);
            fma8(a1lo, a1hi, v0, g01);
            fma8(a0lo, a0hi, v1, g10);
            fma8(a1lo, a1hi, v1, g11);
        }
        if (e < pe) {
            int   c0 = cb[e];
            float v0 = vb[e];
            const unsigned short* r0p = xsrc + (size_t)c0 * 64;
            uint4 g00 = *(const uint4*)(r0p + s8);
            uint4 g01 = *(const uint4*)(r0p + 32 + s8);
            fma8(a0lo, a0hi, v0, g00);
            fma8(a1lo, a1hi, v0, g01);
        }
        short8 af0 = pack_af(a0lo, a0hi);   // A-frag, K-half 0 (k = quad*8+j)
        short8 af1 = pack_af(a1lo, a1hi);   // A-frag, K-half 1 (k = 32+quad*8+j)

        // ---- MFMA: D[16x64] += A[16x64] x W_k[64x64] (two 16x16x32 halves) ----
        const unsigned short* Wp = WTl + pk * 4096;
        short8 b00 = *(const short8*)(Wp + ( 0 + m) * 64 + s8);
        short8 b10 = *(const short8*)(Wp + (16 + m) * 64 + s8);
        short8 b20 = *(const short8*)(Wp + (32 + m) * 64 + s8);
        short8 b30 = *(const short8*)(Wp + (48 + m) * 64 + s8);
        d0 = __builtin_amdgcn_mfma_f32_16x16x32_bf16(af0, b00, d0, 0, 0, 0);
        d1 = __builtin_amdgcn_mfma_f32_16x16x32_bf16(af0, b10, d1, 0, 0, 0);
        d2 = __builtin_amdgcn_mfma_f32_16x16x32_bf16(af0, b20, d2, 0, 0, 0);
        d3 = __builtin_amdgcn_mfma_f32_16x16x32_bf16(af0, b30, d3, 0, 0, 0);
        short8 b01 = *(const short8*)(Wp + ( 0 + m) * 64 + 32 + s8);
        short8 b11 = *(const short8*)(Wp + (16 + m) * 64 + 32 + s8);
        short8 b21 = *(const short8*)(Wp + (32 + m) * 64 + 32 + s8);
        short8 b31 = *(const short8*)(Wp + (48 + m) * 64 + 32 + s8);
        d0 = __builtin_amdgcn_mfma_f32_16x16x32_bf16(af1, b01, d0, 0, 0, 0);
        d1 = __builtin_amdgcn_mfma_f32_16x16x32_bf16(af1, b11, d1, 0, 0, 0);
        d2 = __builtin_amdgcn_mfma_f32_16x16x32_bf16(af1, b21, d2, 0, 0, 0);
        d3 = __builtin_amdgcn_mfma_f32_16x16x32_bf16(af1, b31, d3, 0, 0, 0);
    }

    // ---- epilogue: C layout col=lane&15, row=quad*4+reg -> LDS -> coalesced ----
#pragma unroll
    for (int g = 0; g < 4; ++g) {
        C[(quad * 4 + g) * 65 +  0 + m] = d0[g];
        C[(quad * 4 + g) * 65 + 16 + m] = d1[g];
        C[(quad * 4 + g) * 65 + 32 + m] = d2[g];
        C[(quad * 4 + g) * 65 + 48 + m] = d3[g];
    }
    __builtin_amdgcn_s_waitcnt(0);   // drain lgkm before cross-lane LDS read (same wave)

    int row = lane >> 2;             // 0..15
    int qs  = lane & 3;              // 0..3 (16-channel segment)
    const float* Cr = C + row * 65 + qs * 16;
    float4 v0 = *(const float4*)(Cr + 0);
    float4 v1 = *(const float4*)(Cr + 4);
    float4 v2 = *(const float4*)(Cr + 8);
    float4 v3 = *(const float4*)(Cr + 12);
    if (layer == 2) {
        const uint4* res = (const uint4*)(xp.p[j] + (size_t)(r0 + row) * 64 + qs * 16);
        uint4 ra = res[0];
        uint4 rb = res[1];
        float4 o0 = bf16x4_to_f4(make_uint2(ra.x, ra.y));
        float4 o1 = bf16x4_to_f4(make_uint2(ra.z, ra.w));
        float4 o2 = bf16x4_to_f4(make_uint2(rb.x, rb.y));
        float4 o3 = bf16x4_to_f4(make_uint2(rb.z, rb.w));
        v0.x += o0.x; v0.y += o0.y; v0.z += o0.z; v0.w += o0.w;
        v1.x += o1.x; v1.y += o1.y; v1.z += o1.z; v1.w += o1.w;
        v2.x += o2.x; v2.y += o2.y; v2.z += o2.z; v2.w += o2.w;
        v3.x += o3.x; v3.y += o3.y; v3.z += o3.z; v3.w += o3.w;
    }
    v0.x = fmaxf(v0.x, 0.f); v0.y = fmaxf(v0.y, 0.f); v0.z = fmaxf(v0.z, 0.f); v0.w = fmaxf(v0.w, 0.f);
    v1.x = fmaxf(v1.x, 0.f); v1.y = fmaxf(v1.y, 0.f); v1.z = fmaxf(v1.z, 0.f); v1.w = fmaxf(v1.w, 0.f);
    v2.x = fmaxf(v2.x, 0.f); v2.y = fmaxf(v2.y, 0.f); v2.z = fmaxf(v2.z, 0.f); v2.w = fmaxf(v2.w, 0.f);
    v3.x = fmaxf(v3.x, 0.f); v3.y = fmaxf(v3.y, 0.f); v3.z = fmaxf(v3.z, 0.f); v3.w = fmaxf(v3.w, 0.f);
    uint2 s0 = f4_to_bf16x4(v0);
    uint2 s1 = f4_to_bf16x4(v1);
    uint2 s2 = f4_to_bf16x4(v2);
    uint2 s3 = f4_to_bf16x4(v3);
    uint4* dst = (uint4*)(xout + (size_t)(XOFF[j] + r0 + row) * 64 + qs * 16);
    dst[0] = make_uint4(s0.x, s0.y, s1.x, s1.y);
    dst[1] = make_uint4(s2.x, s2.y, s3.x, s3.y);
}

// ---------------------------------------------------------------------
// 3) pooling stage 1: per-(rank, block) partial sum/sumsq(f64)/max/min
// ---------------------------------------------------------------------
__global__ __launch_bounds__(256) void k_pool1(const unsigned short* __restrict__ xs,
                                               double* __restrict__ psum,
                                               double* __restrict__ psq,
                                               float* __restrict__ pmax,
                                               float* __restrict__ pmin) {
    int rank = blockIdx.x >> 7;
    int blk  = blockIdx.x & 127;
    int c    = threadIdx.x & 63;
    int sub  = threadIdx.x >> 6;
    int N = NRr[rank];
    const unsigned short* xb = xs + (size_t)XOFF[rank] * 64;
    double s = 0.0, q = 0.0;
    float mx = -3.4e38f, mn = 3.4e38f;
    for (int r = blk * 4 + sub; r < N; r += 512) {
        float v = __uint_as_float(((unsigned int)xb[(size_t)r * 64 + c]) << 16);
        s += v; q += (double)v * (double)v;
        mx = fmaxf(mx, v); mn = fminf(mn, v);
    }
    __shared__ double ls[4][64], lq[4][64];
    __shared__ float lmx[4][64], lmn[4][64];
    ls[sub][c] = s; lq[sub][c] = q; lmx[sub][c] = mx; lmn[sub][c] = mn;
    __syncthreads();
    if (sub == 0) {
#pragma unroll
        for (int t = 1; t < 4; ++t) {
            s += ls[t][c]; q += lq[t][c];
            mx = fmaxf(mx, lmx[t][c]); mn = fminf(mn, lmn[t][c]);
        }
        int idx = (rank * 128 + blk) * 64 + c;
        psum[idx] = s; psq[idx] = q; pmax[idx] = mx; pmin[idx] = mn;
    }
}

// ---------------------------------------------------------------------
// 4) fused pooling stage 2 + MLP: 1284 -> 512 -> 128 -> 64 -> 2
// ---------------------------------------------------------------------
__global__ __launch_bounds__(512) void k_tail(const double* __restrict__ psum,
                                              const double* __restrict__ psq,
                                              const float* __restrict__ pmax,
                                              const float* __restrict__ pmin,
                                              const float* __restrict__ gf,
                                              const float* __restrict__ w1, const float* __restrict__ b1,
                                              const float* __restrict__ w2, const float* __restrict__ b2,
                                              const float* __restrict__ w3, const float* __restrict__ b3,
                                              const float* __restrict__ w4, const float* __restrict__ b4,
                                              float* __restrict__ out) {
    __shared__ float sp[1284];
    __shared__ float h1[512];
    __shared__ float h2[128];
    __shared__ float h3[64];
    int tid = threadIdx.x;
    if (tid < 320) {
        int rank = tid >> 6;
        int c    = tid & 63;
        double s = 0.0, q = 0.0;
        float mx = -3.4e38f, mn = 3.4e38f;
        for (int b = 0; b < 128; ++b) {
            int idx = (rank * 128 + b) * 64 + c;
            s += psum[idx]; q += psq[idx];
            mx = fmaxf(mx, pmax[idx]); mn = fminf(mn, pmin[idx]);
        }
        double N = (double)NRr[rank];
        double mean = s / N;
        double var  = q / N - mean * mean;
        if (var < 0.0) var = 0.0;
        double sd = sqrt(var == 0.0 ? 1e-6 : var);
        sp[rank * 256 + c]       = (float)mean;
        sp[rank * 256 + 64 + c]  = (float)sd;
        sp[rank * 256 + 128 + c] = mx;
        sp[rank * 256 + 192 + c] = mn;
        if (rank == 0 && c < 4) sp[1280 + c] = gf[c];
    }
    __syncthreads();
    {
        float a = 0.f;
        for (int k2 = 0; k2 < 1284; ++k2) a += sp[k2] * w1[k2 * 512 + tid];
        h1[tid] = fmaxf(a + b1[tid], 0.f);
    }
    __syncthreads();
    if (tid < 128) {
        float a = 0.f;
        for (int k2 = 0; k2 < 512; ++k2) a += h1[k2] * w2[k2 * 128 + tid];
        h2[tid] = fmaxf(a + b2[tid], 0.f);
    }
    __syncthreads();
    if (tid < 64) {
        float a = 0.f;
        for (int k2 = 0; k2 < 128; ++k2) a += h2[k2] * w3[k2 * 64 + tid];
        h3[tid] = fmaxf(a + b3[tid], 0.f);
    }
    __syncthreads();
    if (tid < 2) {
        float a = 0.f;
        for (int k2 = 0; k2 < 64; ++k2) a += h3[k2] * w4[k2 * 2 + tid];
        a += b4[tid];
        if (tid == 1) a = a * a;
        out[tid] = a;
    }
}

// ---------------------------------------------------------------------
extern "C" void kernel_launch(void* const* d_in, const int* in_sizes, int n_in,
                              void* d_out, int out_size, void* d_ws, size_t ws_size,
                              hipStream_t stream) {
    if (ws_size < WS_NEEDED) {
        hipLaunchKernelGGL(k_diag, dim3(1), dim3(1), 0, stream,
                           (float*)d_out, (float)(ws_size >> 20));
        return;
    }

    const float* x0   = (const float*)d_in[0];
    const float* x1   = (const float*)d_in[1];
    const float* x2   = (const float*)d_in[2];
    const float* x3   = (const float*)d_in[3];
    const float* x4   = (const float*)d_in[4];
    const int*   rows = (const int*)d_in[5];
    const int*   cols = (const int*)d_in[6];
    const float* vals = (const float*)d_in[7];
    const float* gf   = (const float*)d_in[8];
    const float* Wh   = (const float*)d_in[9];
    const float* w1   = (const float*)d_in[10];
    const float* b1   = (const float*)d_in[11];
    const float* w2   = (const float*)d_in[12];
    const float* b2   = (const float*)d_in[13];
    const float* w3   = (const float*)d_in[14];
    const float* b3   = (const float*)d_in[15];
    const float* w4   = (const float*)d_in[16];
    const float* b4   = (const float*)d_in[17];

    char* ws = (char*)d_ws;
    unsigned short* b16in = (unsigned short*)(ws + WS_B16IN);
    unsigned short* b16x  = (unsigned short*)(ws + WS_B16X);
    unsigned short* b16y  = (unsigned short*)(ws + WS_B16Y);
    int*    rptr   = (int*)(ws + WS_PTR);
    unsigned short* WT = (unsigned short*)(ws + WS_WT);
    double* psum   = (double*)(ws + WS_PSUM);
    double* psq    = (double*)(ws + WS_PSQ);
    float*  pmax   = (float*)(ws + WS_PMAX);
    float*  pmin   = (float*)(ws + WS_PMIN);

    XP xp_in; xp_in.p[0] = x0; xp_in.p[1] = x1; xp_in.p[2] = x2; xp_in.p[3] = x3; xp_in.p[4] = x4;
    hipLaunchKernelGGL(k_cvt, dim3((XROWS * 16 + 255) / 256), dim3(256), 0, stream, xp_in, b16in);
    hipLaunchKernelGGL(k_cvtw, dim3((3 * 15 * 4096 + 255) / 256), dim3(256), 0, stream, Wh, WT);
    hipLaunchKernelGGL(k_ptr, dim3((PTR_TOT + 255) / 256), dim3(256), 0, stream, rows, rptr);

    XPB xb_in, xb_x, xb_y;
    for (int i = 0; i < 5; ++i) {
        xb_in.p[i] = b16in + (size_t)XOFF[i] * 64;
        xb_x.p[i]  = b16x  + (size_t)XOFF[i] * 64;
        xb_y.p[i]  = b16y  + (size_t)XOFF[i] * 64;
    }

    // layer 0: b16in -> b16x ; layer 1: b16x -> b16y ; layer 2: b16y -> b16x (+residual)
    hipLaunchKernelGGL(k_fused, dim3(FUSED_BLOCKS), dim3(64), 0, stream,
                       xb_in, cols, vals, rptr, WT, b16x, 0);
    hipLaunchKernelGGL(k_fused, dim3(FUSED_BLOCKS), dim3(64), 0, stream,
                       xb_x, cols, vals, rptr, WT, b16y, 1);
    hipLaunchKernelGGL(k_fused, dim3(FUSED_BLOCKS), dim3(64), 0, stream,
                       xb_y, cols, vals, rptr, WT, b16x, 2);

    hipLaunchKernelGGL(k_pool1, dim3(5 * 128), dim3(256), 0, stream, b16x, psum, psq, pmax, pmin);
    hipLaunchKernelGGL(k_tail, dim3(1), dim3(512), 0, stream, psum, psq, pmax, pmin, gf,
                       w1, b1, w2, b2, w3, b3, w4, b4, (float*)d_out);
}